// Round 19
// baseline (109.644 us; speedup 1.0000x reference)
//
#include <hip/hip_runtime.h>
#include <stdint.h>
#include <math.h>

#define H 8
#define NSEQ 8192
#define D 64
// score scale folded into log2 domain: 1/sqrt(64) * log2(e)
#define SC2 0.18033688011112042f
#define LN2F 0.69314718055994531f
#define THR2 10.0f
#define EPSF 1.1920928955078125e-07f

typedef short v8s __attribute__((ext_vector_type(8)));
typedef float v4f __attribute__((ext_vector_type(4)));
typedef unsigned short ushort_t;

#define MFMA16(a,b,c) __builtin_amdgcn_mfma_f32_16x16x32_bf16((a),(b),(c),0,0,0)
// XOR bank swizzle (G4), 128B rows (K / P-half) and 256B rows (VT)
#define SWZ(row, cb)    (((row)*128) + ((cb) ^ ((((row)&7))<<4)))
#define SWZ256(row, cb) (((row)*256) + ((cb) ^ ((((row)&7))<<4)))

__device__ __forceinline__ float exp2x(float x){         // raw v_exp_f32 (2^x)
  float r; asm("v_exp_f32 %0, %1" : "=v"(r) : "v"(x)); return r;
}
__device__ __forceinline__ unsigned int cvtpk(float a, float b){ // 2xf32 -> packed bf16
  unsigned int r; asm("v_cvt_pk_bf16_f32 %0, %1, %2" : "=v"(r) : "v"(a), "v"(b)); return r;
}
__device__ __forceinline__ ushort_t f2bf(float f){
  union { float f; unsigned int u; } c; c.f = f;
  unsigned int u = c.u + 0x7FFFu + ((c.u >> 16) & 1u);   // RNE
  return (ushort_t)(u >> 16);
}
#define VONES (v8s){0x3F80,0x3F80,0x3F80,0x3F80,0x3F80,0x3F80,0x3F80,0x3F80}

// ---------------- 0. fused prepass+hash (Q,K) + bf16 convert (V) ----------------
__global__ __launch_bounds__(256) void prep_hash(
    const float* __restrict__ q, const float* __restrict__ k, const float* __restrict__ v,
    const float* __restrict__ proj,
    ushort_t* __restrict__ qb, ushort_t* __restrict__ kb, ushort_t* __restrict__ vb,
    int* __restrict__ hq, int* __restrict__ hk)
{
  __shared__ float tile[64][65];
  __shared__ float pj[448];
  __shared__ int pbuf[4][64];
  const int bid = blockIdx.x;            // 3072 = {q,k} 2048 tiles + v 1024 tiles
  const int t = threadIdx.x;
  if (bid >= 2048){                      // V: pure bf16 convert
    const int tix = bid - 2048;
    size_t off = (size_t)tix*4096 + t*16;
    float4 f0 = *(const float4*)(v + off);
    float4 f1 = *(const float4*)(v + off + 4);
    float4 f2 = *(const float4*)(v + off + 8);
    float4 f3 = *(const float4*)(v + off + 12);
    uint4 o0, o1;
    o0.x = cvtpk(f0.x, f0.y);  o0.y = cvtpk(f0.z, f0.w);
    o0.z = cvtpk(f1.x, f1.y);  o0.w = cvtpk(f1.z, f1.w);
    o1.x = cvtpk(f2.x, f2.y);  o1.y = cvtpk(f2.z, f2.w);
    o1.z = cvtpk(f3.x, f3.y);  o1.w = cvtpk(f3.z, f3.w);
    *(uint4*)(vb + off) = o0;
    *(uint4*)(vb + off + 8) = o1;
    return;
  }
  const int isk = bid & 1;
  const int tix = bid >> 1;
  const int rowbase = tix << 6;
  const float* src = isk ? k : q;
  ushort_t* dstb = isk ? kb : qb;
  int* dsth = isk ? hk : hq;
  for (int i = t; i < 448; i += 256) pj[i] = proj[i];
  {
    const int r = t >> 2, cg = (t & 3) << 4;
    const float* s = src + (size_t)(rowbase + r)*64 + cg;
    float4 f0 = *(const float4*)(s);
    float4 f1 = *(const float4*)(s + 4);
    float4 f2 = *(const float4*)(s + 8);
    float4 f3 = *(const float4*)(s + 12);
    tile[r][cg+0]=f0.x;  tile[r][cg+1]=f0.y;  tile[r][cg+2]=f0.z;  tile[r][cg+3]=f0.w;
    tile[r][cg+4]=f1.x;  tile[r][cg+5]=f1.y;  tile[r][cg+6]=f1.z;  tile[r][cg+7]=f1.w;
    tile[r][cg+8]=f2.x;  tile[r][cg+9]=f2.y;  tile[r][cg+10]=f2.z; tile[r][cg+11]=f2.w;
    tile[r][cg+12]=f3.x; tile[r][cg+13]=f3.y; tile[r][cg+14]=f3.z; tile[r][cg+15]=f3.w;
    uint4 o0, o1;
    o0.x = cvtpk(f0.x, f0.y);  o0.y = cvtpk(f0.z, f0.w);
    o0.z = cvtpk(f1.x, f1.y);  o0.w = cvtpk(f1.z, f1.w);
    o1.x = cvtpk(f2.x, f2.y);  o1.y = cvtpk(f2.z, f2.w);
    o1.z = cvtpk(f3.x, f3.y);  o1.w = cvtpk(f3.z, f3.w);
    *(uint4*)(dstb + (size_t)(rowbase + r)*64 + cg) = o0;
    *(uint4*)(dstb + (size_t)(rowbase + r)*64 + cg + 8) = o1;
  }
  __syncthreads();
  { // hash: 256 threads = 64 rows x 4 proj-groups; EXACT serial d-order per dot
    const int r = t & 63, pg = t >> 6;
    const int p2 = (pg < 3) ? (pg + 4) : 6;   // pg=3 -> duplicate p6 (discarded)
    float d0 = 0.0f, d1 = 0.0f;
    for (int d = 0; d < 64; ++d){
      float x = tile[r][d];
      d0 = fmaf(x, pj[d*7 + pg], d0);
      d1 = fmaf(x, pj[d*7 + p2], d1);
    }
    int pb = (d0 > 0.0f ? (1 << pg) : 0);
    if (pg < 3 && d1 > 0.0f) pb |= (1 << (pg + 4));
    pbuf[pg][r] = pb;
  }
  __syncthreads();
  if (t < 64){
    int b = pbuf[0][t] | pbuf[1][t] | pbuf[2][t] | pbuf[3][t];
    dsth[rowbase + t] = b ^ (b >> 1);          // gray code == _PERM
  }
}

// ---------------- Threefry-2x32-20 (partitionable PRNG) ----------------
__device__ __forceinline__ void tf2x32(uint32_t k0, uint32_t k1,
                                       uint32_t x0, uint32_t x1,
                                       uint32_t& o0, uint32_t& o1)
{
  uint32_t ks0 = k0, ks1 = k1, ks2 = k0 ^ k1 ^ 0x1BD11BDAu;
  x0 += ks0; x1 += ks1;
#define RND(r) { x0 += x1; x1 = (x1 << (r)) | (x1 >> (32-(r))); x1 ^= x0; }
  RND(13) RND(15) RND(26) RND(6)  x0 += ks1; x1 += ks2 + 1u;
  RND(17) RND(29) RND(16) RND(24) x0 += ks2; x1 += ks0 + 2u;
  RND(13) RND(15) RND(26) RND(6)  x0 += ks0; x1 += ks1 + 3u;
  RND(17) RND(29) RND(16) RND(24) x0 += ks1; x1 += ks2 + 4u;
  RND(13) RND(15) RND(26) RND(6)  x0 += ks2; x1 += ks0 + 5u;
#undef RND
  o0 = x0; o1 = x1;
}

// ================= MFMA flash helpers (KVBLK=128, split-PV halves) =================
__device__ __forceinline__ void qk8(const v8s qf[2], const char* Ks, int lo, int hi, v4f sa[8]){
  __builtin_amdgcn_s_setprio(1);
#pragma unroll
  for (int st = 0; st < 8; ++st){
#pragma unroll
    for (int kc = 0; kc < 2; ++kc){
      v8s bf = *(const v8s*)(Ks + SWZ(st*16 + lo, kc*64 + hi*16));
      sa[st] = MFMA16(qf[kc], bf, sa[st]);
    }
  }
  __builtin_amdgcn_s_setprio(0);
}

// Pw = 2KB per-wave [16 q][64 col'64]; VT = [64 d][2 halves x 64 col'64]
__device__ __forceinline__ void sm_pv8s(v4f sa[8], char* Pw, const char* VTs,
                                        int lo, int hi, float m[4], v4f o[5]){
  float tm[4];
  bool grow = false;
#pragma unroll
  for (int reg = 0; reg < 4; ++reg){
    float a = fmaxf(fmaxf(sa[0][reg], sa[1][reg]), fmaxf(sa[2][reg], sa[3][reg]));
    float b = fmaxf(fmaxf(sa[4][reg], sa[5][reg]), fmaxf(sa[6][reg], sa[7][reg]));
    tm[reg] = fmaxf(a, b);
    grow = grow || (tm[reg] > m[reg] + THR2);
  }
  if (__any(grow)){
#pragma unroll
    for (int reg = 0; reg < 4; ++reg){
      float t = tm[reg];
      t = fmaxf(t, __shfl_xor(t, 1));
      t = fmaxf(t, __shfl_xor(t, 2));
      t = fmaxf(t, __shfl_xor(t, 4));
      t = fmaxf(t, __shfl_xor(t, 8));
      float mn = fmaxf(m[reg], t);
      float corr = exp2x(m[reg] - mn);
      m[reg] = mn;
#pragma unroll
      for (int dt = 0; dt < 5; ++dt) o[dt][reg] *= corr;
    }
  }
#pragma unroll
  for (int hh = 0; hh < 2; ++hh){
#pragma unroll
    for (int reg = 0; reg < 4; ++reg){
      float mr = m[reg];
      uint2 pw;   // keys half hh: {lo,16+lo,32+lo,48+lo} -> cols'64 4lo..4lo+3
      pw.x = cvtpk(exp2x(sa[hh*4+0][reg]-mr), exp2x(sa[hh*4+1][reg]-mr));
      pw.y = cvtpk(exp2x(sa[hh*4+2][reg]-mr), exp2x(sa[hh*4+3][reg]-mr));
      *(uint2*)(Pw + SWZ(hi*4 + reg, 8*lo)) = pw;
    }
    asm volatile("" ::: "memory");   // order P writes before PV reads (same wave)
    __builtin_amdgcn_s_setprio(1);
#pragma unroll
    for (int kb = 0; kb < 2; ++kb){
      v8s pa = *(const v8s*)(Pw + SWZ(lo, kb*64 + hi*16));
#pragma unroll
      for (int dt = 0; dt < 4; ++dt){
        v8s vbr = *(const v8s*)(VTs + SWZ256(dt*16 + lo, hh*128 + kb*64 + hi*16));
        o[dt] = MFMA16(pa, vbr, o[dt]);
      }
      o[4] = MFMA16(pa, VONES, o[4]);
    }
    __builtin_amdgcn_s_setprio(0);
    asm volatile("" ::: "memory");   // half done before P overwritten
  }
}

// V-stage repack into half layout (packed uint2 writes, proven low-conflict)
__device__ __forceinline__ void vt_write_h(char* VTs, uint2 vr0, uint2 vr1, uint2 vr2, uint2 vr3,
                                           int vdg, int vlo, int vsth){
  const int cb = vsth*128 + vlo*8;
  uint2 w;
  w.x = (vr0.x & 0xFFFFu) | ((vr1.x & 0xFFFFu) << 16);
  w.y = (vr2.x & 0xFFFFu) | ((vr3.x & 0xFFFFu) << 16);
  *(uint2*)(VTs + SWZ256(vdg*4 + 0, cb)) = w;
  w.x = (vr0.x >> 16) | (vr1.x & 0xFFFF0000u);
  w.y = (vr2.x >> 16) | (vr3.x & 0xFFFF0000u);
  *(uint2*)(VTs + SWZ256(vdg*4 + 1, cb)) = w;
  w.x = (vr0.y & 0xFFFFu) | ((vr1.y & 0xFFFFu) << 16);
  w.y = (vr2.y & 0xFFFFu) | ((vr3.y & 0xFFFFu) << 16);
  *(uint2*)(VTs + SWZ256(vdg*4 + 2, cb)) = w;
  w.x = (vr0.y >> 16) | (vr1.y & 0xFFFF0000u);
  w.y = (vr2.y >> 16) | (vr3.y & 0xFFFF0000u);
  *(uint2*)(VTs + SWZ256(vdg*4 + 3, cb)) = w;
}

// ---------------- fused: diagonal causal (512 blocks, LDS dbuf) + sort (48 tail) ----------------
__global__ __launch_bounds__(512, 4) void diag_sort(
    const ushort_t* __restrict__ qb, const ushort_t* __restrict__ kb, const ushort_t* __restrict__ vb,
    float* __restrict__ out, float* __restrict__ lse,
    const int* __restrict__ hq, const int* __restrict__ hk,
    int* __restrict__ q100, int* __restrict__ k100,
    int* __restrict__ q101, int* __restrict__ k101,
    int* __restrict__ s100, int* __restrict__ s101)
{
  __shared__ __align__(16) char lds[81920];
  const int bid0 = blockIdx.x;
  const int tid = threadIdx.x;

  if (bid0 >= 512){
    // ======== sort + sampling (tail blocks; backfill behind finishing diag) ========
    const int sbid = bid0 - 512;
    unsigned char  (*hist)[128] = (unsigned char (*)[128])lds;            // 16KB
    unsigned short (*off )[128] = (unsigned short(*)[128])(lds + 16384);  // 32KB
    int* bstart = (int*)(lds + 49152);                                    // 512B
    const int t = tid;
    if (t < 128){ // fused threefry sampling: 48*128 = 6144 = 2048 + 4096
      int gid = sbid*128 + t;
      int level, span, idx; int* outp;
      if (gid < 2048){ level = 100; span = 4096; outp = s100; idx = gid; }
      else           { level = 101; span = 2048; outp = s101; idx = gid - 2048; }
      uint32_t r0, r1; tf2x32(0u, 42u, 0u, (uint32_t)level, r0, r1);
      uint32_t k20, k21; tf2x32(r0, r1, 0u, 1u, k20, k21);
      uint32_t o0, o1; tf2x32(k20, k21, 0u, (uint32_t)idx, o0, o1);
      outp[idx] = (int)((o0 ^ o1) % (uint32_t)span);
    }
    const int* src = nullptr; int n = 0, base = 0; int* outp = nullptr;
    if (sbid < 8)       { int h = sbid;     src = hq + h*NSEQ + 4096;        n = 4096; base = 4096;          outp = q100 + h*4096; }
    else if (sbid < 16) { int h = sbid - 8; src = hk + h*NSEQ;               n = 4096; base = 0;             outp = k100 + h*4096; }
    else if (sbid < 32) { int id = sbid-16; int h = id>>1, p = id&1;
                          src = hq + h*NSEQ + p*4096 + 2048;                 n = 2048; base = p*4096 + 2048; outp = q101 + id*2048; }
    else                { int id = sbid-32; int h = id>>1, p = id&1;
                          src = hk + h*NSEQ + p*4096;                        n = 2048; base = p*4096;       outp = k101 + id*2048; }
    const int chunk = n >> 7;   // <=32, fits uchar counts
    if (t < 128) for (int b = 0; b < 128; ++b) hist[t][b] = 0;
    __syncthreads();
    const int* mysrc = src + (t & 127) * chunk;
    if (t < 128) for (int i = 0; i < chunk; ++i) hist[t][mysrc[i]]++;
    __syncthreads();
    if (t < 128){
      int s = 0;
      for (int tt = 0; tt < 128; ++tt) s += hist[tt][t];
      bstart[t] = s;
    }
    __syncthreads();
    if (t == 0){
      int run = 0;
      for (int b = 0; b < 128; ++b){ int c = bstart[b]; bstart[b] = run; run += c; }
    }
    __syncthreads();
    if (t < 128){
      unsigned int run = (unsigned int)bstart[t];
      for (int tt = 0; tt < 128; ++tt){ off[tt][t] = (unsigned short)run; run += hist[tt][t]; }
    }
    __syncthreads();
    if (t < 128){
      for (int i = 0; i < chunk; ++i){
        int hsh = mysrc[i];
        unsigned short pos = off[t][hsh]++;
        outp[pos] = base + t * chunk + i;
      }
    }
    return;
  }

  // ======== diag: near-pair (2j, 2j+1), CU-balanced, LDS double-buffered ========
  //   t = b0 ^ b8; j = t ? 15-G : G, G = (b>>5)&7; inst = (b0<<4)|((b>>1)&15).
  char* Ks0 = lds;              // [128 key][64 d]   16KB
  char* Ks1 = lds + 16384;
  char* VT0 = lds + 32768;      // [64 d][2x64 col'] 16KB
  char* VT1 = lds + 49152;
  char* Ps  = lds + 65536;      // 8 x [16 q][64 col'64] 16KB
  const int b = bid0;
  const int G = (b >> 5) & 7;
  const int tt_ = (b & 1) ^ ((b >> 8) & 1);
  const int j = tt_ ? (15 - G) : G;
  const int inst = ((b & 1) << 4) | ((b >> 1) & 15);
  const int h = inst >> 2, tblk = inst & 3;
  const size_t hoff = (size_t)h * NSEQ * D;
  const ushort_t* qh = qb + hoff; const ushort_t* kh = kb + hoff; const ushort_t* vh = vb + hoff;
  const int blkbase = tblk * 2048;
  const int w = tid >> 6, lane = tid & 63;
  const int lo = lane & 15, hi = lane >> 4;
  char* Pw = Ps + w*2048;
  const int kr = tid >> 2, kq = tid & 3;                       // K staging
  const int vlo = tid & 15, vdg = (tid >> 4) & 15, vsth = tid >> 8;  // V staging

  const int qt = (w < 4) ? (2*j + 1) : (2*j);  // both tiles need j+1 iterations
  const int nkt = j + 1;
  const int qpos0 = qt*64 + (w & 3)*16;

  v8s qf[2];
  {
    const ushort_t* r = qh + (size_t)(blkbase + qpos0 + lo) * D;
    qf[0] = *(const v8s*)(r + hi*8);
    qf[1] = *(const v8s*)(r + 32 + hi*8);
  }
  const v4f vz = {0.0f, 0.0f, 0.0f, 0.0f};
  v4f o[5] = {vz, vz, vz, vz, vz};
  float m[4] = {-INFINITY, -INFINITY, -INFINITY, -INFINITY};

  uint4 kreg0, kreg1; uint2 vr0, vr1, vr2, vr3;
#define DLOAD(kt) { \
    const ushort_t* ksr = kh + (size_t)(blkbase + (kt)*128 + kr)*D + kq*16; \
    kreg0 = *(const uint4*)ksr; \
    kreg1 = *(const uint4*)(ksr + 8); \
    const ushort_t* vs = vh + (size_t)(blkbase + (kt)*128 + vsth*64 + vlo)*D + vdg*4; \
    vr0 = *(const uint2*)(vs); \
    vr1 = *(const uint2*)(vs + 16*D); \
    vr2 = *(const uint2*)(vs + 32*D); \
    vr3 = *(const uint2*)(vs + 48*D); }
#define DSTAGE(KSP, VTP) { \
    *(uint4*)((KSP) + SWZ(kr, kq*32))      = kreg0; \
    *(uint4*)((KSP) + SWZ(kr, kq*32 + 16)) = kreg1; \
    vt_write_h((VTP), vr0, vr1, vr2, vr3, vdg, vlo, vsth); }

  DLOAD(0);
  DSTAGE(Ks0, VT0);
#pragma unroll 1
  for (int kt = 0; kt < nkt; ++kt){
    __syncthreads();                           // buf[kt&1] staged by all waves
    char* Ksc = (kt & 1) ? Ks1 : Ks0;
    const char* VTc = (kt & 1) ? VT1 : VT0;
    char* Ksn = (kt & 1) ? Ks0 : Ks1;
    char* VTn = (kt & 1) ? VT0 : VT1;
    const bool more = (kt + 1 < nkt);
    if (more) DLOAD(kt+1);                     // HBM latency hides under compute
    {
      v4f sa[8] = {vz, vz, vz, vz, vz, vz, vz, vz};
      qk8(qf, Ksc, lo, hi, sa);
#pragma unroll
      for (int st = 0; st < 8; ++st) sa[st] *= SC2;
      if (kt == nkt - 1){
#pragma unroll
        for (int st = 0; st < 8; ++st){
          int kpos = kt*128 + st*16 + lo;
#pragma unroll
          for (int reg = 0; reg < 4; ++reg)
            if (kpos > qpos0 + hi*4 + reg) sa[st][reg] = -INFINITY;
        }
      }
      sm_pv8s(sa, Pw, VTc, lo, hi, m, o);
    }
    if (more) DSTAGE(Ksn, VTn);                // other buffer: no WAR with readers
  }
#undef DLOAD
#undef DSTAGE
#pragma unroll
  for (int reg = 0; reg < 4; ++reg){
    int rw = blkbase + qpos0 + hi*4 + reg;
    float lsum = o[4][reg];
    float inv = 1.0f / lsum;
#pragma unroll
    for (int dt = 0; dt < 4; ++dt)
      out[hoff + (size_t)rw*D + dt*16 + lo] = o[dt][reg] * inv;
    if (lo == 0) lse[h*NSEQ + rw] = m[reg]*LN2F + logf(lsum);
  }
}

// ---------------- fused nc: level 101 (in-place) + level 100 (to scratch) ----------------
__global__ __launch_bounds__(512, 4) void nc_both(
    const ushort_t* __restrict__ qb, const ushort_t* __restrict__ kb, const ushort_t* __restrict__ vb,
    float* __restrict__ out, float* __restrict__ lse,
    const int* __restrict__ q101, const int* __restrict__ k101, const int* __restrict__ s101,
    const int* __restrict__ q100, const int* __restrict__ k100, const int* __restrict__ s100,
    ushort_t* __restrict__ a100, float* __restrict__ lse100)
{
  __shared__ __align__(16) char Ks[16384];
  __shared__ __align__(16) char VTs[16384];
  __shared__ __align__(16) char Ps[8][2048];
  __shared__ unsigned int ilds[512];
  const int bid = blockIdx.x;               // [0,256) = 101, [256,512) = 100
  const bool lvl101 = bid < 256;
  int inst, jb; float delta2; int seglen;
  const int *qi, *ki, *sp;
  if (lvl101){
    int xcd = bid & 7, sl = bid >> 3; inst = xcd*2 + (sl >> 4); jb = sl & 15;
    delta2 = 3.0f; seglen = 2048;
    qi = q101 + inst*seglen; ki = k101 + inst*seglen; sp = s101 + inst*256;
  } else {
    int b2 = bid - 256; inst = b2 & 7; jb = b2 >> 3;
    delta2 = 4.0f; seglen = 4096;
    qi = q100 + inst*seglen; ki = k100 + inst*seglen; sp = s100 + inst*256;
  }
  const int h = lvl101 ? (inst >> 1) : inst;
  const int qblk = jb >> 1;
  const size_t hoff = (size_t)h * NSEQ * D;
  const ushort_t* qh = qb + hoff; const ushort_t* kh = kb + hoff; const ushort_t* vh = vb + hoff;
  const int tid = threadIdx.x;
  const int w = tid >> 6, lane = tid & 63;
  const int lo = lane & 15, hi = lane >> 4;
  char* Pw = Ps[w];
  const int kr = tid >> 2, kq = tid & 3;
  const int vlo = tid & 15, vdg = (tid >> 4) & 15, vsth = tid >> 8;

  { // stage index tables (one-time): sorted keys + sampled keys w/ mask bit
    if (tid < 256){
      ilds[tid] = (unsigned int)ki[qblk*256 + tid];
    } else {
      int s = sp[tid - 256];
      unsigned int krow = (unsigned int)ki[s];
      if ((s >> 8) == qblk) krow |= 0x80000000u;
      ilds[tid] = krow;
    }
  }
  int orig[4];
  v8s qf[2];
  {
    int qrl = qi[jb*128 + w*16 + lo];
    const ushort_t* r = qh + (size_t)qrl * D;
    qf[0] = *(const v8s*)(r + hi*8);
    qf[1] = *(const v8s*)(r + 32 + hi*8);
#pragma unroll
    for (int reg = 0; reg < 4; ++reg) orig[reg] = qi[jb*128 + w*16 + hi*4 + reg];
  }
  const v4f vz = {0.0f, 0.0f, 0.0f, 0.0f};
  v4f o[5] = {vz, vz, vz, vz, vz};
  float m[4] = {-INFINITY, -INFINITY, -INFINITY, -INFINITY};
  __syncthreads();    // ilds ready

  uint4 kreg0, kreg1; uint2 vr0, vr1, vr2, vr3;
#define NLOAD(kt) { \
    unsigned int krow = ilds[(kt)*128 + kr] & 0x7FFFFFFFu; \
    const ushort_t* ksr = kh + (size_t)krow*D + kq*16; \
    kreg0 = *(const uint4*)ksr; \
    kreg1 = *(const uint4*)(ksr + 8); \
    unsigned int g0 = ilds[(kt)*128 + vsth*64 + vlo     ] & 0x7FFFFFFFu; \
    unsigned int g1 = ilds[(kt)*128 + vsth*64 + 16 + vlo] & 0x7FFFFFFFu; \
    unsigned int g2 = ilds[(kt)*128 + vsth*64 + 32 + vlo] & 0x7FFFFFFFu; \
    unsigned int g3 = ilds[(kt)*128 + vsth*64 + 48 + vlo] & 0x7FFFFFFFu; \
    vr0 = *(const uint2*)(vh + (size_t)g0*D + vdg*4); \
    vr1 = *(const uint2*)(vh + (size_t)g1*D + vdg*4); \
    vr2 = *(const uint2*)(vh + (size_t)g2*D + vdg*4); \
    vr3 = *(const uint2*)(vh + (size_t)g3*D + vdg*4); }

  NLOAD(0);
#pragma unroll 1
  for (int kt = 0; kt < 4; ++kt){
    *(uint4*)(Ks + SWZ(kr, kq*32))      = kreg0;
    *(uint4*)(Ks + SWZ(kr, kq*32 + 16)) = kreg1;
    vt_write_h(VTs, vr0, vr1, vr2, vr3, vdg, vlo, vsth);
    __syncthreads();
    if (kt + 1 < 4) NLOAD(kt+1);
    v4f sa[8] = {vz, vz, vz, vz, vz, vz, vz, vz};
    qk8(qf, Ks, lo, hi, sa);
    if (kt < 2){
#pragma unroll
      for (int st = 0; st < 8; ++st) sa[st] *= SC2;
    } else {
#pragma unroll
      for (int st = 0; st < 8; ++st){
        if (ilds[kt*128 + st*16 + lo] >> 31) sa[st] = (v4f){-INFINITY, -INFINITY, -INFINITY, -INFINITY};
        else                                 sa[st] = sa[st]*SC2 + delta2;
      }
    }
    sm_pv8s(sa, Pw, VTs, lo, hi, m, o);
    __syncthreads();
  }
#undef NLOAD
  if (lvl101){
    // in-place merge (_add_attn) — rows disjoint from nc100 scratch
#pragma unroll
    for (int reg = 0; reg < 4; ++reg){
      int og = orig[reg];
      float lsum = o[4][reg];
      float l1v = lse[h*NSEQ + og];
      float l2v = m[reg]*LN2F + logf(lsum);
      float c = 1.0f / (1.0f + __expf(l2v - l1v));
      float inv = (1.0f - c) / lsum;
#pragma unroll
      for (int dt = 0; dt < 4; ++dt){
        float* ap = out + hoff + (size_t)og*D + dt*16 + lo;
        *ap = c * (*ap) + inv * o[dt][reg];
      }
      if (lo == 0) lse[h*NSEQ + og] = l1v - logf(c + EPSF);
    }
  } else {
    // scratch write: normalized attn (bf16) + lse
#pragma unroll
    for (int reg = 0; reg < 4; ++reg){
      int og = orig[reg];
      float lsum = o[4][reg];
      float inv = 1.0f / lsum;
      ushort_t* arow = a100 + ((size_t)h*NSEQ + og)*D;
#pragma unroll
      for (int dt = 0; dt < 4; ++dt)
        arow[dt*16 + lo] = f2bf(o[dt][reg] * inv);
      if (lo == 0) lse100[h*NSEQ + og] = m[reg]*LN2F + logf(lsum);
    }
  }
}

// ---------------- final merge: rows [4096,8192) of each head ----------------
__global__ __launch_bounds__(256) void merge_kernel(
    float* __restrict__ out, const float* __restrict__ lse,
    const ushort_t* __restrict__ a100, const float* __restrict__ lse100)
{
  const int gid = blockIdx.x * 256 + threadIdx.x;   // 524288 threads x 4 floats
  const size_t e = (size_t)gid * 4;
  const int h = (int)(e >> 18);                     // 4096*64 = 2^18 per head
  const int rem = (int)(e & 262143);
  const int og = 4096 + (rem >> 6);
  const size_t row = (size_t)h*NSEQ + og;
  const float l1 = lse[row];
  const float l2 = lse100[row];
  const float c = 1.0f / (1.0f + __expf(l2 - l1));
  const float ic = 1.0f - c;
  float* op = out + ((size_t)h*NSEQ*D) + (size_t)og*D + (rem & 63);
  float4 ov = *(float4*)op;
  uint2 av = *(const uint2*)(a100 + row*D + (rem & 63));
  float a0 = __uint_as_float((av.x & 0xFFFFu) << 16);
  float a1 = __uint_as_float((av.x & 0xFFFF0000u));
  float a2 = __uint_as_float((av.y & 0xFFFFu) << 16);
  float a3 = __uint_as_float((av.y & 0xFFFF0000u));
  ov.x = c*ov.x + ic*a0;
  ov.y = c*ov.y + ic*a1;
  ov.z = c*ov.z + ic*a2;
  ov.w = c*ov.w + ic*a3;
  *(float4*)op = ov;
}

// ---------------- launch ----------------
extern "C" void kernel_launch(void* const* d_in, const int* in_sizes, int n_in,
                              void* d_out, int out_size, void* d_ws, size_t ws_size,
                              hipStream_t stream)
{
  const float* q    = (const float*)d_in[0];
  const float* k    = (const float*)d_in[1];
  const float* v    = (const float*)d_in[2];
  const float* proj = (const float*)d_in[3];
  float* out = (float*)d_out;

  char* ws = (char*)d_ws;
  float* lse = (float*)ws;                       // 256 KB
  int* hq   = (int*)(ws + 262144);               // 256 KB
  int* hk   = (int*)(ws + 524288);               // 256 KB
  int* q100 = (int*)(ws + 786432);               // 128 KB
  int* k100 = (int*)(ws + 917504);               // 128 KB
  int* q101 = (int*)(ws + 1048576);              // 128 KB
  int* k101 = (int*)(ws + 1179648);              // 128 KB
  int* s100 = (int*)(ws + 1310720);              // 8 KB
  int* s101 = (int*)(ws + 1318912);              // 16 KB
  ushort_t* qb = (ushort_t*)(ws + 1335296);      // 8 MB each
  ushort_t* kb = qb + (size_t)H*NSEQ*D;
  ushort_t* vb = kb + (size_t)H*NSEQ*D;
  ushort_t* a100 = vb + (size_t)H*NSEQ*D;        // 8 MB (bf16)
  float* lse100 = (float*)(a100 + (size_t)H*NSEQ*D);  // 256 KB

  prep_hash    <<<dim3(3072), dim3(256), 0, stream>>>(q, k, v, proj, qb, kb, vb, hq, hk);
  diag_sort    <<<dim3(560),  dim3(512), 0, stream>>>(qb, kb, vb, out, lse, hq, hk,
                                                      q100, k100, q101, k101, s100, s101);
  nc_both      <<<dim3(512),  dim3(512), 0, stream>>>(qb, kb, vb, out, lse,
                                                      q101, k101, s101, q100, k100, s100,
                                                      a100, lse100);
  merge_kernel <<<dim3(2048), dim3(256), 0, stream>>>(out, lse, a100, lse100);
}

// Round 20
// 95.964 us; speedup vs baseline: 1.1426x; 1.1426x over previous
//
#include <hip/hip_runtime.h>
#include <stdint.h>
#include <math.h>

#define H 8
#define NSEQ 8192
#define D 64
// score scale folded into log2 domain: 1/sqrt(64) * log2(e)
#define SC2 0.18033688011112042f
#define LN2F 0.69314718055994531f
#define THR2 10.0f
#define EPSF 1.1920928955078125e-07f

typedef short v8s __attribute__((ext_vector_type(8)));
typedef float v4f __attribute__((ext_vector_type(4)));
typedef unsigned short ushort_t;

#define MFMA16(a,b,c) __builtin_amdgcn_mfma_f32_16x16x32_bf16((a),(b),(c),0,0,0)
// XOR bank swizzle (G4), 128B rows (K / P-half) and 256B rows (VT)
#define SWZ(row, cb)    (((row)*128) + ((cb) ^ ((((row)&7))<<4)))
#define SWZ256(row, cb) (((row)*256) + ((cb) ^ ((((row)&7))<<4)))

__device__ __forceinline__ float exp2x(float x){         // raw v_exp_f32 (2^x)
  float r; asm("v_exp_f32 %0, %1" : "=v"(r) : "v"(x)); return r;
}
__device__ __forceinline__ unsigned int cvtpk(float a, float b){ // 2xf32 -> packed bf16
  unsigned int r; asm("v_cvt_pk_bf16_f32 %0, %1, %2" : "=v"(r) : "v"(a), "v"(b)); return r;
}
__device__ __forceinline__ ushort_t f2bf(float f){
  union { float f; unsigned int u; } c; c.f = f;
  unsigned int u = c.u + 0x7FFFu + ((c.u >> 16) & 1u);   // RNE
  return (ushort_t)(u >> 16);
}
#define VONES (v8s){0x3F80,0x3F80,0x3F80,0x3F80,0x3F80,0x3F80,0x3F80,0x3F80}

// ---------------- 0. fused prepass+hash (Q,K) + bf16 convert (V) ----------------
__global__ __launch_bounds__(256) void prep_hash(
    const float* __restrict__ q, const float* __restrict__ k, const float* __restrict__ v,
    const float* __restrict__ proj,
    ushort_t* __restrict__ qb, ushort_t* __restrict__ kb, ushort_t* __restrict__ vb,
    int* __restrict__ hq, int* __restrict__ hk)
{
  __shared__ float tile[64][65];
  __shared__ float pj[448];
  __shared__ int pbuf[4][64];
  const int bid = blockIdx.x;            // 3072 = {q,k} 2048 tiles + v 1024 tiles
  const int t = threadIdx.x;
  if (bid >= 2048){                      // V: pure bf16 convert
    const int tix = bid - 2048;
    size_t off = (size_t)tix*4096 + t*16;
    float4 f0 = *(const float4*)(v + off);
    float4 f1 = *(const float4*)(v + off + 4);
    float4 f2 = *(const float4*)(v + off + 8);
    float4 f3 = *(const float4*)(v + off + 12);
    uint4 o0, o1;
    o0.x = cvtpk(f0.x, f0.y);  o0.y = cvtpk(f0.z, f0.w);
    o0.z = cvtpk(f1.x, f1.y);  o0.w = cvtpk(f1.z, f1.w);
    o1.x = cvtpk(f2.x, f2.y);  o1.y = cvtpk(f2.z, f2.w);
    o1.z = cvtpk(f3.x, f3.y);  o1.w = cvtpk(f3.z, f3.w);
    *(uint4*)(vb + off) = o0;
    *(uint4*)(vb + off + 8) = o1;
    return;
  }
  const int isk = bid & 1;
  const int tix = bid >> 1;
  const int rowbase = tix << 6;
  const float* src = isk ? k : q;
  ushort_t* dstb = isk ? kb : qb;
  int* dsth = isk ? hk : hq;
  for (int i = t; i < 448; i += 256) pj[i] = proj[i];
  {
    const int r = t >> 2, cg = (t & 3) << 4;
    const float* s = src + (size_t)(rowbase + r)*64 + cg;
    float4 f0 = *(const float4*)(s);
    float4 f1 = *(const float4*)(s + 4);
    float4 f2 = *(const float4*)(s + 8);
    float4 f3 = *(const float4*)(s + 12);
    tile[r][cg+0]=f0.x;  tile[r][cg+1]=f0.y;  tile[r][cg+2]=f0.z;  tile[r][cg+3]=f0.w;
    tile[r][cg+4]=f1.x;  tile[r][cg+5]=f1.y;  tile[r][cg+6]=f1.z;  tile[r][cg+7]=f1.w;
    tile[r][cg+8]=f2.x;  tile[r][cg+9]=f2.y;  tile[r][cg+10]=f2.z; tile[r][cg+11]=f2.w;
    tile[r][cg+12]=f3.x; tile[r][cg+13]=f3.y; tile[r][cg+14]=f3.z; tile[r][cg+15]=f3.w;
    uint4 o0, o1;
    o0.x = cvtpk(f0.x, f0.y);  o0.y = cvtpk(f0.z, f0.w);
    o0.z = cvtpk(f1.x, f1.y);  o0.w = cvtpk(f1.z, f1.w);
    o1.x = cvtpk(f2.x, f2.y);  o1.y = cvtpk(f2.z, f2.w);
    o1.z = cvtpk(f3.x, f3.y);  o1.w = cvtpk(f3.z, f3.w);
    *(uint4*)(dstb + (size_t)(rowbase + r)*64 + cg) = o0;
    *(uint4*)(dstb + (size_t)(rowbase + r)*64 + cg + 8) = o1;
  }
  __syncthreads();
  { // hash: 256 threads = 64 rows x 4 proj-groups; EXACT serial d-order per dot
    const int r = t & 63, pg = t >> 6;
    const int p2 = (pg < 3) ? (pg + 4) : 6;   // pg=3 -> duplicate p6 (discarded)
    float d0 = 0.0f, d1 = 0.0f;
    for (int d = 0; d < 64; ++d){
      float x = tile[r][d];
      d0 = fmaf(x, pj[d*7 + pg], d0);
      d1 = fmaf(x, pj[d*7 + p2], d1);
    }
    int pb = (d0 > 0.0f ? (1 << pg) : 0);
    if (pg < 3 && d1 > 0.0f) pb |= (1 << (pg + 4));
    pbuf[pg][r] = pb;
  }
  __syncthreads();
  if (t < 64){
    int b = pbuf[0][t] | pbuf[1][t] | pbuf[2][t] | pbuf[3][t];
    dsth[rowbase + t] = b ^ (b >> 1);          // gray code == _PERM
  }
}

// ---------------- Threefry-2x32-20 (partitionable PRNG) ----------------
__device__ __forceinline__ void tf2x32(uint32_t k0, uint32_t k1,
                                       uint32_t x0, uint32_t x1,
                                       uint32_t& o0, uint32_t& o1)
{
  uint32_t ks0 = k0, ks1 = k1, ks2 = k0 ^ k1 ^ 0x1BD11BDAu;
  x0 += ks0; x1 += ks1;
#define RND(r) { x0 += x1; x1 = (x1 << (r)) | (x1 >> (32-(r))); x1 ^= x0; }
  RND(13) RND(15) RND(26) RND(6)  x0 += ks1; x1 += ks2 + 1u;
  RND(17) RND(29) RND(16) RND(24) x0 += ks2; x1 += ks0 + 2u;
  RND(13) RND(15) RND(26) RND(6)  x0 += ks0; x1 += ks1 + 3u;
  RND(17) RND(29) RND(16) RND(24) x0 += ks1; x1 += ks2 + 4u;
  RND(13) RND(15) RND(26) RND(6)  x0 += ks2; x1 += ks0 + 5u;
#undef RND
  o0 = x0; o1 = x1;
}

// ================= MFMA flash helpers (KVBLK=128, split-PV halves) =================
__device__ __forceinline__ void qk8(const v8s qf[2], const char* Ks, int lo, int hi, v4f sa[8]){
  __builtin_amdgcn_s_setprio(1);
#pragma unroll
  for (int st = 0; st < 8; ++st){
#pragma unroll
    for (int kc = 0; kc < 2; ++kc){
      v8s bf = *(const v8s*)(Ks + SWZ(st*16 + lo, kc*64 + hi*16));
      sa[st] = MFMA16(qf[kc], bf, sa[st]);
    }
  }
  __builtin_amdgcn_s_setprio(0);
}

// Pw = 2KB per-wave [16 q][64 col'64]; VT = [64 d][2 halves x 64 col'64]
__device__ __forceinline__ void sm_pv8s(v4f sa[8], char* Pw, const char* VTs,
                                        int lo, int hi, float m[4], v4f o[5]){
  float tm[4];
  bool grow = false;
#pragma unroll
  for (int reg = 0; reg < 4; ++reg){
    float a = fmaxf(fmaxf(sa[0][reg], sa[1][reg]), fmaxf(sa[2][reg], sa[3][reg]));
    float b = fmaxf(fmaxf(sa[4][reg], sa[5][reg]), fmaxf(sa[6][reg], sa[7][reg]));
    tm[reg] = fmaxf(a, b);
    grow = grow || (tm[reg] > m[reg] + THR2);
  }
  if (__any(grow)){
#pragma unroll
    for (int reg = 0; reg < 4; ++reg){
      float t = tm[reg];
      t = fmaxf(t, __shfl_xor(t, 1));
      t = fmaxf(t, __shfl_xor(t, 2));
      t = fmaxf(t, __shfl_xor(t, 4));
      t = fmaxf(t, __shfl_xor(t, 8));
      float mn = fmaxf(m[reg], t);
      float corr = exp2x(m[reg] - mn);
      m[reg] = mn;
#pragma unroll
      for (int dt = 0; dt < 5; ++dt) o[dt][reg] *= corr;
    }
  }
#pragma unroll
  for (int hh = 0; hh < 2; ++hh){
#pragma unroll
    for (int reg = 0; reg < 4; ++reg){
      float mr = m[reg];
      uint2 pw;   // keys half hh: {lo,16+lo,32+lo,48+lo} -> cols'64 4lo..4lo+3
      pw.x = cvtpk(exp2x(sa[hh*4+0][reg]-mr), exp2x(sa[hh*4+1][reg]-mr));
      pw.y = cvtpk(exp2x(sa[hh*4+2][reg]-mr), exp2x(sa[hh*4+3][reg]-mr));
      *(uint2*)(Pw + SWZ(hi*4 + reg, 8*lo)) = pw;
    }
    asm volatile("" ::: "memory");   // order P writes before PV reads (same wave)
    __builtin_amdgcn_s_setprio(1);
#pragma unroll
    for (int kb = 0; kb < 2; ++kb){
      v8s pa = *(const v8s*)(Pw + SWZ(lo, kb*64 + hi*16));
#pragma unroll
      for (int dt = 0; dt < 4; ++dt){
        v8s vbr = *(const v8s*)(VTs + SWZ256(dt*16 + lo, hh*128 + kb*64 + hi*16));
        o[dt] = MFMA16(pa, vbr, o[dt]);
      }
      o[4] = MFMA16(pa, VONES, o[4]);
    }
    __builtin_amdgcn_s_setprio(0);
    asm volatile("" ::: "memory");   // half done before P overwritten
  }
}

// V-stage repack into half layout (packed uint2 writes, proven low-conflict)
__device__ __forceinline__ void vt_write_h(char* VTs, uint2 vr0, uint2 vr1, uint2 vr2, uint2 vr3,
                                           int vdg, int vlo, int vsth){
  const int cb = vsth*128 + vlo*8;
  uint2 w;
  w.x = (vr0.x & 0xFFFFu) | ((vr1.x & 0xFFFFu) << 16);
  w.y = (vr2.x & 0xFFFFu) | ((vr3.x & 0xFFFFu) << 16);
  *(uint2*)(VTs + SWZ256(vdg*4 + 0, cb)) = w;
  w.x = (vr0.x >> 16) | (vr1.x & 0xFFFF0000u);
  w.y = (vr2.x >> 16) | (vr3.x & 0xFFFF0000u);
  *(uint2*)(VTs + SWZ256(vdg*4 + 1, cb)) = w;
  w.x = (vr0.y & 0xFFFFu) | ((vr1.y & 0xFFFFu) << 16);
  w.y = (vr2.y & 0xFFFFu) | ((vr3.y & 0xFFFFu) << 16);
  *(uint2*)(VTs + SWZ256(vdg*4 + 2, cb)) = w;
  w.x = (vr0.y >> 16) | (vr1.y & 0xFFFF0000u);
  w.y = (vr2.y >> 16) | (vr3.y & 0xFFFF0000u);
  *(uint2*)(VTs + SWZ256(vdg*4 + 3, cb)) = w;
}

// ---------------- fused: diagonal causal (512 blocks) + sort/sample (48 tail) ----------------
__global__ __launch_bounds__(512, 4) void diag_sort(
    const ushort_t* __restrict__ qb, const ushort_t* __restrict__ kb, const ushort_t* __restrict__ vb,
    float* __restrict__ out, float* __restrict__ lse,
    const int* __restrict__ hq, const int* __restrict__ hk,
    int* __restrict__ q100, int* __restrict__ k100,
    int* __restrict__ q101, int* __restrict__ k101,
    int* __restrict__ s100, int* __restrict__ s101)
{
  __shared__ __align__(16) char lds[49664];
  const int bid0 = blockIdx.x;
  const int tid = threadIdx.x;

  if (bid0 >= 512){
    // ======== sort + sampling (tail blocks; backfill behind finishing diag) ========
    const int sbid = bid0 - 512;
    unsigned char  (*hist)[128] = (unsigned char (*)[128])lds;            // 16KB
    unsigned short (*off )[128] = (unsigned short(*)[128])(lds + 16384);  // 32KB
    int* bstart = (int*)(lds + 49152);                                    // 512B
    const int t = tid;
    if (t < 128){ // fused threefry sampling: 48*128 = 6144 = 2048 + 4096
      int gid = sbid*128 + t;
      int level, span, idx; int* outp;
      if (gid < 2048){ level = 100; span = 4096; outp = s100; idx = gid; }
      else           { level = 101; span = 2048; outp = s101; idx = gid - 2048; }
      uint32_t r0, r1; tf2x32(0u, 42u, 0u, (uint32_t)level, r0, r1);
      uint32_t k20, k21; tf2x32(r0, r1, 0u, 1u, k20, k21);
      uint32_t o0, o1; tf2x32(k20, k21, 0u, (uint32_t)idx, o0, o1);
      outp[idx] = (int)((o0 ^ o1) % (uint32_t)span);
    }
    const int* src = nullptr; int n = 0, base = 0; int* outp = nullptr;
    if (sbid < 8)       { int h = sbid;     src = hq + h*NSEQ + 4096;        n = 4096; base = 4096;          outp = q100 + h*4096; }
    else if (sbid < 16) { int h = sbid - 8; src = hk + h*NSEQ;               n = 4096; base = 0;             outp = k100 + h*4096; }
    else if (sbid < 32) { int id = sbid-16; int h = id>>1, p = id&1;
                          src = hq + h*NSEQ + p*4096 + 2048;                 n = 2048; base = p*4096 + 2048; outp = q101 + id*2048; }
    else                { int id = sbid-32; int h = id>>1, p = id&1;
                          src = hk + h*NSEQ + p*4096;                        n = 2048; base = p*4096;       outp = k101 + id*2048; }
    const int chunk = n >> 7;   // <=32, fits uchar counts
    if (t < 128) for (int b = 0; b < 128; ++b) hist[t][b] = 0;
    __syncthreads();
    const int* mysrc = src + (t & 127) * chunk;
    if (t < 128) for (int i = 0; i < chunk; ++i) hist[t][mysrc[i]]++;
    __syncthreads();
    if (t < 128){
      int s = 0;
      for (int tt = 0; tt < 128; ++tt) s += hist[tt][t];
      bstart[t] = s;
    }
    __syncthreads();
    if (t == 0){
      int run = 0;
      for (int b = 0; b < 128; ++b){ int c = bstart[b]; bstart[b] = run; run += c; }
    }
    __syncthreads();
    if (t < 128){
      unsigned int run = (unsigned int)bstart[t];
      for (int tt = 0; tt < 128; ++tt){ off[tt][t] = (unsigned short)run; run += hist[tt][t]; }
    }
    __syncthreads();
    if (t < 128){
      for (int i = 0; i < chunk; ++i){
        int hsh = mysrc[i];
        unsigned short pos = off[t][hsh]++;
        outp[pos] = base + t * chunk + i;
      }
    }
    return;
  }

  // ======== diagonal causal flash: near-pair (2j, 2j+1), zero idle waves ========
  // CU-balanced dispatch: co-resident blocks get complementary lengths (j, 15-j)
  // under BOTH pairing hypotheses (bid^1 and bid^256 share a CU):
  //   t = b0 ^ b8; j = t ? 15-G : G, G = (b>>5)&7; inst = (b0<<4)|((b>>1)&15).
  // Coverage: each (inst, j) in [0,32)x[0,16) appears exactly once over b in [0,512).
  char* Ks  = lds;              // [128 key][64 d]   16KB
  char* VTs = lds + 16384;      // [64 d][2x64 col'] 16KB
  char* Ps  = lds + 32768;      // 8 x [16 q][64 col'64] 16KB
  const int b = bid0;
  const int G = (b >> 5) & 7;
  const int tt_ = (b & 1) ^ ((b >> 8) & 1);
  const int j = tt_ ? (15 - G) : G;
  const int inst = ((b & 1) << 4) | ((b >> 1) & 15);
  const int h = inst >> 2, tblk = inst & 3;
  const size_t hoff = (size_t)h * NSEQ * D;
  const ushort_t* qh = qb + hoff; const ushort_t* kh = kb + hoff; const ushort_t* vh = vb + hoff;
  const int blkbase = tblk * 2048;
  const int w = tid >> 6, lane = tid & 63;
  const int lo = lane & 15, hi = lane >> 4;
  char* Pw = Ps + w*2048;
  const int kr = tid >> 2, kq = tid & 3;                       // K staging
  const int vlo = tid & 15, vdg = (tid >> 4) & 15, vsth = tid >> 8;  // V staging

  const int qt = (w < 4) ? (2*j + 1) : (2*j);  // both tiles need j+1 iterations
  const int nkt = j + 1;
  const int qpos0 = qt*64 + (w & 3)*16;

  v8s qf[2];
  {
    const ushort_t* r = qh + (size_t)(blkbase + qpos0 + lo) * D;
    qf[0] = *(const v8s*)(r + hi*8);
    qf[1] = *(const v8s*)(r + 32 + hi*8);
  }
  const v4f vz = {0.0f, 0.0f, 0.0f, 0.0f};
  v4f o[5] = {vz, vz, vz, vz, vz};
  float m[4] = {-INFINITY, -INFINITY, -INFINITY, -INFINITY};

  uint4 kreg0, kreg1; uint2 vr0, vr1, vr2, vr3;
#define DLOAD(kt) { \
    const ushort_t* ksr = kh + (size_t)(blkbase + (kt)*128 + kr)*D + kq*16; \
    kreg0 = *(const uint4*)ksr; \
    kreg1 = *(const uint4*)(ksr + 8); \
    const ushort_t* vs = vh + (size_t)(blkbase + (kt)*128 + vsth*64 + vlo)*D + vdg*4; \
    vr0 = *(const uint2*)(vs); \
    vr1 = *(const uint2*)(vs + 16*D); \
    vr2 = *(const uint2*)(vs + 32*D); \
    vr3 = *(const uint2*)(vs + 48*D); }

  DLOAD(0);
#pragma unroll 1
  for (int kt = 0; kt < nkt; ++kt){
    *(uint4*)(Ks + SWZ(kr, kq*32))      = kreg0;
    *(uint4*)(Ks + SWZ(kr, kq*32 + 16)) = kreg1;
    vt_write_h(VTs, vr0, vr1, vr2, vr3, vdg, vlo, vsth);
    __syncthreads();
    if (kt + 1 < nkt) DLOAD(kt+1);
    {
      v4f sa[8] = {vz, vz, vz, vz, vz, vz, vz, vz};
      qk8(qf, Ks, lo, hi, sa);
#pragma unroll
      for (int st = 0; st < 8; ++st) sa[st] *= SC2;
      if (kt == nkt - 1){
#pragma unroll
        for (int st = 0; st < 8; ++st){
          int kpos = kt*128 + st*16 + lo;
#pragma unroll
          for (int reg = 0; reg < 4; ++reg)
            if (kpos > qpos0 + hi*4 + reg) sa[st][reg] = -INFINITY;
        }
      }
      sm_pv8s(sa, Pw, VTs, lo, hi, m, o);
    }
    __syncthreads();
  }
#undef DLOAD
#pragma unroll
  for (int reg = 0; reg < 4; ++reg){
    int rw = blkbase + qpos0 + hi*4 + reg;
    float lsum = o[4][reg];
    float inv = 1.0f / lsum;
#pragma unroll
    for (int dt = 0; dt < 4; ++dt)
      out[hoff + (size_t)rw*D + dt*16 + lo] = o[dt][reg] * inv;
    if (lo == 0) lse[h*NSEQ + rw] = m[reg]*LN2F + logf(lsum);
  }
}

// ---------------- fused nc: level 101 (in-place) + level 100 (to scratch) ----------------
// Index tables LDS-staged once per block: ilds[0..256) = sorted keys of qblk,
// ilds[256..512) = gathered sampled keys with block-match mask in bit 31.
// Layout identity: 256 + (kt-2)*128 == kt*128, so entry = ilds[kt*128 + pos].
__global__ __launch_bounds__(512, 4) void nc_both(
    const ushort_t* __restrict__ qb, const ushort_t* __restrict__ kb, const ushort_t* __restrict__ vb,
    float* __restrict__ out, float* __restrict__ lse,
    const int* __restrict__ q101, const int* __restrict__ k101, const int* __restrict__ s101,
    const int* __restrict__ q100, const int* __restrict__ k100, const int* __restrict__ s100,
    ushort_t* __restrict__ a100, float* __restrict__ lse100)
{
  __shared__ __align__(16) char Ks[16384];
  __shared__ __align__(16) char VTs[16384];
  __shared__ __align__(16) char Ps[8][2048];
  __shared__ unsigned int ilds[512];
  const int bid = blockIdx.x;               // [0,256) = 101, [256,512) = 100
  const bool lvl101 = bid < 256;
  int inst, jb; float delta2; int seglen;
  const int *qi, *ki, *sp;
  if (lvl101){
    int xcd = bid & 7, sl = bid >> 3; inst = xcd*2 + (sl >> 4); jb = sl & 15;
    delta2 = 3.0f; seglen = 2048;
    qi = q101 + inst*seglen; ki = k101 + inst*seglen; sp = s101 + inst*256;
  } else {
    int b2 = bid - 256; inst = b2 & 7; jb = b2 >> 3;
    delta2 = 4.0f; seglen = 4096;
    qi = q100 + inst*seglen; ki = k100 + inst*seglen; sp = s100 + inst*256;
  }
  const int h = lvl101 ? (inst >> 1) : inst;
  const int qblk = jb >> 1;
  const size_t hoff = (size_t)h * NSEQ * D;
  const ushort_t* qh = qb + hoff; const ushort_t* kh = kb + hoff; const ushort_t* vh = vb + hoff;
  const int tid = threadIdx.x;
  const int w = tid >> 6, lane = tid & 63;
  const int lo = lane & 15, hi = lane >> 4;
  char* Pw = Ps[w];
  const int kr = tid >> 2, kq = tid & 3;
  const int vlo = tid & 15, vdg = (tid >> 4) & 15, vsth = tid >> 8;

  { // stage index tables (one-time): sorted keys + sampled keys w/ mask bit
    if (tid < 256){
      ilds[tid] = (unsigned int)ki[qblk*256 + tid];
    } else {
      int s = sp[tid - 256];
      unsigned int krow = (unsigned int)ki[s];
      if ((s >> 8) == qblk) krow |= 0x80000000u;
      ilds[tid] = krow;
    }
  }
  int orig[4];
  v8s qf[2];
  {
    int qrl = qi[jb*128 + w*16 + lo];
    const ushort_t* r = qh + (size_t)qrl * D;
    qf[0] = *(const v8s*)(r + hi*8);
    qf[1] = *(const v8s*)(r + 32 + hi*8);
#pragma unroll
    for (int reg = 0; reg < 4; ++reg) orig[reg] = qi[jb*128 + w*16 + hi*4 + reg];
  }
  const v4f vz = {0.0f, 0.0f, 0.0f, 0.0f};
  v4f o[5] = {vz, vz, vz, vz, vz};
  float m[4] = {-INFINITY, -INFINITY, -INFINITY, -INFINITY};
  __syncthreads();    // ilds ready

  uint4 kreg0, kreg1; uint2 vr0, vr1, vr2, vr3;
#define NLOAD(kt) { \
    unsigned int krow = ilds[(kt)*128 + kr] & 0x7FFFFFFFu; \
    const ushort_t* ksr = kh + (size_t)krow*D + kq*16; \
    kreg0 = *(const uint4*)ksr; \
    kreg1 = *(const uint4*)(ksr + 8); \
    unsigned int g0 = ilds[(kt)*128 + vsth*64 + vlo     ] & 0x7FFFFFFFu; \
    unsigned int g1 = ilds[(kt)*128 + vsth*64 + 16 + vlo] & 0x7FFFFFFFu; \
    unsigned int g2 = ilds[(kt)*128 + vsth*64 + 32 + vlo] & 0x7FFFFFFFu; \
    unsigned int g3 = ilds[(kt)*128 + vsth*64 + 48 + vlo] & 0x7FFFFFFFu; \
    vr0 = *(const uint2*)(vh + (size_t)g0*D + vdg*4); \
    vr1 = *(const uint2*)(vh + (size_t)g1*D + vdg*4); \
    vr2 = *(const uint2*)(vh + (size_t)g2*D + vdg*4); \
    vr3 = *(const uint2*)(vh + (size_t)g3*D + vdg*4); }

  NLOAD(0);
#pragma unroll 1
  for (int kt = 0; kt < 4; ++kt){
    *(uint4*)(Ks + SWZ(kr, kq*32))      = kreg0;
    *(uint4*)(Ks + SWZ(kr, kq*32 + 16)) = kreg1;
    vt_write_h(VTs, vr0, vr1, vr2, vr3, vdg, vlo, vsth);
    __syncthreads();
    if (kt + 1 < 4) NLOAD(kt+1);
    v4f sa[8] = {vz, vz, vz, vz, vz, vz, vz, vz};
    qk8(qf, Ks, lo, hi, sa);
    if (kt < 2){
#pragma unroll
      for (int st = 0; st < 8; ++st) sa[st] *= SC2;
    } else {
#pragma unroll
      for (int st = 0; st < 8; ++st){
        if (ilds[kt*128 + st*16 + lo] >> 31) sa[st] = (v4f){-INFINITY, -INFINITY, -INFINITY, -INFINITY};
        else                                 sa[st] = sa[st]*SC2 + delta2;
      }
    }
    sm_pv8s(sa, Pw, VTs, lo, hi, m, o);
    __syncthreads();
  }
#undef NLOAD
  if (lvl101){
    // in-place merge (_add_attn) — rows disjoint from nc100 scratch
#pragma unroll
    for (int reg = 0; reg < 4; ++reg){
      int og = orig[reg];
      float lsum = o[4][reg];
      float l1v = lse[h*NSEQ + og];
      float l2v = m[reg]*LN2F + logf(lsum);
      float c = 1.0f / (1.0f + __expf(l2v - l1v));
      float inv = (1.0f - c) / lsum;
#pragma unroll
      for (int dt = 0; dt < 4; ++dt){
        float* ap = out + hoff + (size_t)og*D + dt*16 + lo;
        *ap = c * (*ap) + inv * o[dt][reg];
      }
      if (lo == 0) lse[h*NSEQ + og] = l1v - logf(c + EPSF);
    }
  } else {
    // scratch write: normalized attn (bf16) + lse
#pragma unroll
    for (int reg = 0; reg < 4; ++reg){
      int og = orig[reg];
      float lsum = o[4][reg];
      float inv = 1.0f / lsum;
      ushort_t* arow = a100 + ((size_t)h*NSEQ + og)*D;
#pragma unroll
      for (int dt = 0; dt < 4; ++dt)
        arow[dt*16 + lo] = f2bf(o[dt][reg] * inv);
      if (lo == 0) lse100[h*NSEQ + og] = m[reg]*LN2F + logf(lsum);
    }
  }
}

// ---------------- final merge: rows [4096,8192) of each head ----------------
__global__ __launch_bounds__(256) void merge_kernel(
    float* __restrict__ out, const float* __restrict__ lse,
    const ushort_t* __restrict__ a100, const float* __restrict__ lse100)
{
  const int gid = blockIdx.x * 256 + threadIdx.x;   // 524288 threads x 4 floats
  const size_t e = (size_t)gid * 4;
  const int h = (int)(e >> 18);                     // 4096*64 = 2^18 per head
  const int rem = (int)(e & 262143);
  const int og = 4096 + (rem >> 6);
  const size_t row = (size_t)h*NSEQ + og;
  const float l1 = lse[row];
  const float l2 = lse100[row];
  const float c = 1.0f / (1.0f + __expf(l2 - l1));
  const float ic = 1.0f - c;
  float* op = out + ((size_t)h*NSEQ*D) + (size_t)og*D + (rem & 63);
  float4 ov = *(float4*)op;
  uint2 av = *(const uint2*)(a100 + row*D + (rem & 63));
  float a0 = __uint_as_float((av.x & 0xFFFFu) << 16);
  float a1 = __uint_as_float((av.x & 0xFFFF0000u));
  float a2 = __uint_as_float((av.y & 0xFFFFu) << 16);
  float a3 = __uint_as_float((av.y & 0xFFFF0000u));
  ov.x = c*ov.x + ic*a0;
  ov.y = c*ov.y + ic*a1;
  ov.z = c*ov.z + ic*a2;
  ov.w = c*ov.w + ic*a3;
  *(float4*)op = ov;
}

// ---------------- launch ----------------
extern "C" void kernel_launch(void* const* d_in, const int* in_sizes, int n_in,
                              void* d_out, int out_size, void* d_ws, size_t ws_size,
                              hipStream_t stream)
{
  const float* q    = (const float*)d_in[0];
  const float* k    = (const float*)d_in[1];
  const float* v    = (const float*)d_in[2];
  const float* proj = (const float*)d_in[3];
  float* out = (float*)d_out;

  char* ws = (char*)d_ws;
  float* lse = (float*)ws;                       // 256 KB
  int* hq   = (int*)(ws + 262144);               // 256 KB
  int* hk   = (int*)(ws + 524288);               // 256 KB
  int* q100 = (int*)(ws + 786432);               // 128 KB
  int* k100 = (int*)(ws + 917504);               // 128 KB
  int* q101 = (int*)(ws + 1048576);              // 128 KB
  int* k101 = (int*)(ws + 1179648);              // 128 KB
  int* s100 = (int*)(ws + 1310720);              // 8 KB
  int* s101 = (int*)(ws + 1318912);              // 16 KB
  ushort_t* qb = (ushort_t*)(ws + 1335296);      // 8 MB each
  ushort_t* kb = qb + (size_t)H*NSEQ*D;
  ushort_t* vb = kb + (size_t)H*NSEQ*D;
  ushort_t* a100 = vb + (size_t)H*NSEQ*D;        // 8 MB (bf16)
  float* lse100 = (float*)(a100 + (size_t)H*NSEQ*D);  // 256 KB

  prep_hash    <<<dim3(3072), dim3(256), 0, stream>>>(q, k, v, proj, qb, kb, vb, hq, hk);
  diag_sort    <<<dim3(560),  dim3(512), 0, stream>>>(qb, kb, vb, out, lse, hq, hk,
                                                      q100, k100, q101, k101, s100, s101);
  nc_both      <<<dim3(512),  dim3(512), 0, stream>>>(qb, kb, vb, out, lse,
                                                      q101, k101, s101, q100, k100, s100,
                                                      a100, lse100);
  merge_kernel <<<dim3(2048), dim3(256), 0, stream>>>(out, lse, a100, lse100);
}